// Round 8
// baseline (394.663 us; speedup 1.0000x reference)
//
#include <hip/hip_runtime.h>
#include <hip/hip_bf16.h>

#define B_  8
#define C_  512
#define NN  16384
#define SPL 8
#define KB_ (NN / SPL)   // 2048 per gram block
#define TT  (KB_ / 64)   // 32 K-tiles of 64

typedef _Float16 half8 __attribute__((ext_vector_type(8)));
typedef float    f32x4 __attribute__((ext_vector_type(4)));

__device__ __forceinline__ unsigned short f2h(float x) {
    union { _Float16 h; unsigned short u; } cv;
    cv.h = (_Float16)x;
    return cv.u;
}

__device__ __forceinline__ void gload16(const unsigned short* src, unsigned short* ldst) {
    __builtin_amdgcn_global_load_lds(
        (const __attribute__((address_space(1))) void*)src,
        (__attribute__((address_space(3))) void*)ldst,
        16, 0, 0);
}

__global__ void ws_probe_kernel(float* out, float v) { out[0] = v; }

// ---------- kernel 1: pack fp32 [b][n][c] -> f16 transposed [b][c][n] ----------
__global__ __launch_bounds__(256) void pack_kernel(const float* __restrict__ in,
                                                   unsigned short* __restrict__ qT) {
    __shared__ unsigned short lh[64][72];
    int t  = threadIdx.x;
    int n0 = blockIdx.x * 64;
    int c0 = blockIdx.y * 64;
    int b  = blockIdx.z;
    const float* ib = in + ((size_t)b * NN + n0) * C_ + c0;
#pragma unroll
    for (int p = 0; p < 4; ++p) {
        int nl = p * 16 + (t >> 4);
        int cl = (t & 15) * 4;
        float4 v = *(const float4*)(ib + (size_t)nl * C_ + cl);
        lh[cl + 0][nl] = f2h(v.x);
        lh[cl + 1][nl] = f2h(v.y);
        lh[cl + 2][nl] = f2h(v.z);
        lh[cl + 3][nl] = f2h(v.w);
    }
    __syncthreads();
    size_t obase = ((size_t)b * C_ + c0) * NN + n0;
#pragma unroll
    for (int p = 0; p < 2; ++p) {
        int cr = p * 32 + (t >> 3);
        int nf = (t & 7) * 8;
        *(uint4*)(qT + obase + (size_t)cr * NN + nf) = *(const uint4*)&lh[cr][nf];
    }
}

// ---------- kernel 2: Gram partials, 256x256 tile, BK=64, pipelined ----------
// grid 256: b = bid&7 (XCD locality), r=bid>>3: tile=r&3 (tc,td), split=r>>2
// P layout: [split(8)][b][512][512] fp32
__global__ __launch_bounds__(512, 2) void gram_kernel(const unsigned short* __restrict__ qT,
                                                      float* __restrict__ P) {
    // A,B tiles: [256 rows][64 f16] = 32KB each, double-buffered, st_16x32 swizzle
    __shared__ unsigned short sA[2][16384];
    __shared__ unsigned short sB[2][16384];
    int t = threadIdx.x, lane = t & 63, wave = t >> 6;
    int wr = wave >> 2, wc = wave & 3;           // 2 x 4 wave grid
    int bid = blockIdx.x;
    int b = bid & 7, r = bid >> 3;
    int tile = r & 3, split = r >> 2;
    int tc = tile >> 1, td = tile & 1;
    size_t qb = (size_t)b * C_ * NN;
    const unsigned short* Ap = qT + qb + (size_t)(tc * 256) * NN + (size_t)split * KB_;
    const unsigned short* Bp = qT + qb + (size_t)(td * 256) * NN + (size_t)split * KB_;

    f32x4 acc[8][4];
#pragma unroll
    for (int m = 0; m < 8; ++m)
#pragma unroll
        for (int n = 0; n < 4; ++n) acc[m][n] = (f32x4){0.f, 0.f, 0.f, 0.f};

    // staging: per half (128 rows x 64 f16 = 16KB = 1024 x 16B chunks), 2 chunks/thread.
    // dest is LINEAR (c*16); source pre-swizzled: u = o ^ (((o>>9)&1)<<5)
    int o0 = t * 16,         u0 = o0 ^ (((o0 >> 9) & 1) << 5);
    int o1 = (t + 512) * 16, u1 = o1 ^ (((o1 >> 9) & 1) << 5);
    int rih0 = u0 >> 7, k0 = (u0 & 127) >> 1;
    int rih1 = u1 >> 7, k1 = (u1 & 127) >> 1;

#define STAGE(dst, dd, h, panel, kt)                                                        \
    do {                                                                                    \
        gload16((panel) + (size_t)((h)*128 + rih0) * NN + (kt)*64 + k0,                     \
                &dst[dd][(h)*8192 + t * 8]);                                                \
        gload16((panel) + (size_t)((h)*128 + rih1) * NN + (kt)*64 + k1,                     \
                &dst[dd][(h)*8192 + (t + 512) * 8]);                                        \
    } while (0)

    int g16 = (lane >> 4) * 16;  // k-slot byte offset within 128B row
#define AFRAG(dd, row, ks) \
    (*(const half8*)((const char*)&sA[dd][0] + (((row)*128 + (ks)*64 + g16) ^ (((row)&4) << 3))))
#define BFRAG(dd, row, ks) \
    (*(const half8*)((const char*)&sB[dd][0] + (((row)*128 + (ks)*64 + g16) ^ (((row)&4) << 3))))

    // prologue: stage tile 0 (order A0,B0,B1,A1), need first 3 halves -> vmcnt(2)
    STAGE(sA, 0, 0, Ap, 0);
    STAGE(sB, 0, 0, Bp, 0);
    STAGE(sB, 0, 1, Bp, 0);
    STAGE(sA, 0, 1, Ap, 0);
    asm volatile("s_waitcnt vmcnt(2)" ::: "memory");
    __builtin_amdgcn_s_barrier();

    for (int kt = 0; kt < TT; ++kt) {
        int d = kt & 1, nd = d ^ 1;
        // ---- region 1: quads (A-half0 x B-half0) and (A-half0 x B-half1) ----
        half8 aF[4][2], b0F[2][2], b1F[2][2];
#pragma unroll
        for (int m = 0; m < 4; ++m) {
            int row = wr * 64 + m * 16 + (lane & 15);
#pragma unroll
            for (int ks = 0; ks < 2; ++ks) aF[m][ks] = AFRAG(d, row, ks);
        }
#pragma unroll
        for (int n = 0; n < 2; ++n) {
            int row0 = wc * 32 + n * 16 + (lane & 15);
#pragma unroll
            for (int ks = 0; ks < 2; ++ks) {
                b0F[n][ks] = BFRAG(d, row0, ks);
                b1F[n][ks] = BFRAG(d, (row0 + 128), ks);
            }
        }
        if (kt + 1 < TT) {
            STAGE(sA, nd, 0, Ap, kt + 1);
            STAGE(sB, nd, 0, Bp, kt + 1);
            STAGE(sB, nd, 1, Bp, kt + 1);
        }
        __builtin_amdgcn_s_setprio(1);
#pragma unroll
        for (int m = 0; m < 4; ++m)
#pragma unroll
            for (int n = 0; n < 2; ++n)
#pragma unroll
                for (int ks = 0; ks < 2; ++ks) {
                    acc[m][n]     = __builtin_amdgcn_mfma_f32_16x16x32_f16(aF[m][ks], b0F[n][ks], acc[m][n],     0, 0, 0);
                    acc[m][n + 2] = __builtin_amdgcn_mfma_f32_16x16x32_f16(aF[m][ks], b1F[n][ks], acc[m][n + 2], 0, 0, 0);
                }
        __builtin_amdgcn_s_setprio(0);
        if (kt + 1 < TT) {
            asm volatile("s_waitcnt vmcnt(6)" ::: "memory");   // A-half1 of THIS tile landed
        } else {
            asm volatile("s_waitcnt vmcnt(0)" ::: "memory");   // last tile: no trailing stages
        }
        __builtin_amdgcn_s_barrier();
        // ---- region 2: quads (A-half1 x B-half1) and (A-half1 x B-half0), B frags cached ----
#pragma unroll
        for (int m = 0; m < 4; ++m) {
            int row = 128 + wr * 64 + m * 16 + (lane & 15);
#pragma unroll
            for (int ks = 0; ks < 2; ++ks) aF[m][ks] = AFRAG(d, row, ks);
        }
        if (kt + 1 < TT) STAGE(sA, nd, 1, Ap, kt + 1);
        __builtin_amdgcn_s_setprio(1);
#pragma unroll
        for (int m = 0; m < 4; ++m)
#pragma unroll
            for (int n = 0; n < 2; ++n)
#pragma unroll
                for (int ks = 0; ks < 2; ++ks) {
                    acc[m + 4][n + 2] = __builtin_amdgcn_mfma_f32_16x16x32_f16(aF[m][ks], b1F[n][ks], acc[m + 4][n + 2], 0, 0, 0);
                    acc[m + 4][n]     = __builtin_amdgcn_mfma_f32_16x16x32_f16(aF[m][ks], b0F[n][ks], acc[m + 4][n],     0, 0, 0);
                }
        __builtin_amdgcn_s_setprio(0);
        asm volatile("s_waitcnt vmcnt(2)" ::: "memory");       // next tile's A0,B0,B1 landed
        __builtin_amdgcn_s_barrier();
    }

    float* out = P + ((size_t)(split * 8 + b)) * (C_ * C_);
#pragma unroll
    for (int m = 0; m < 8; ++m) {
        int row0 = tc * 256 + wr * 64 + (m & 3) * 16 + (m >> 2) * 128 + (lane >> 4) * 4;
#pragma unroll
        for (int n = 0; n < 4; ++n) {
            int col = td * 256 + wc * 32 + (n & 1) * 16 + (n >> 1) * 128 + (lane & 15);
#pragma unroll
            for (int j = 0; j < 4; ++j)
                out[(size_t)(row0 + j) * C_ + col] = acc[m][n][j];
        }
    }
#undef STAGE
#undef AFRAG
#undef BFRAG
}

// ---------- kernel 3: sum splits + reversed softmax -> W^T f16 [b][d][c] ----------
// G symmetric (single flavor), softmax(max-G) == softmax(-G): w = exp(minG - G)/sum
__global__ __launch_bounds__(256) void softmax_kernel(const float* __restrict__ P,
                                                      unsigned short* __restrict__ WT) {
    __shared__ unsigned short lw[C_ * 4];
    int t = threadIdx.x, lane = t & 63, wave = t >> 6;
    int b = blockIdx.y;
    int c = blockIdx.x * 4 + wave;
    const float* base = P + (size_t)b * (C_ * C_) + (size_t)c * C_;

    float g[8];
    float mn = 3.4e38f;
#pragma unroll
    for (int k = 0; k < 8; ++k) {
        int d = k * 64 + lane;
        float v = 0.f;
#pragma unroll
        for (int s = 0; s < 8; ++s) v += base[(size_t)s * (8 * C_ * C_) + d];
        g[k] = v;
        mn = fminf(mn, v);
    }
#pragma unroll
    for (int o = 32; o; o >>= 1) mn = fminf(mn, __shfl_xor(mn, o));
    float w[8];
    float sum = 0.f;
#pragma unroll
    for (int k = 0; k < 8; ++k) { w[k] = __expf(mn - g[k]); sum += w[k]; }
#pragma unroll
    for (int o = 32; o; o >>= 1) sum += __shfl_xor(sum, o);
    float inv = 1.0f / sum;
#pragma unroll
    for (int k = 0; k < 8; ++k) {
        int d = k * 64 + lane;
        lw[d * 4 + wave] = f2h(w[k] * inv);
    }
    __syncthreads();
    int c0 = blockIdx.x * 4;
    for (int d = t; d < C_; d += 256)
        *(ushort4*)(WT + ((size_t)b * C_ + d) * C_ + c0) = *(ushort4*)&lw[d * 4];
}

// ---------- kernel 4: value = q @ W, out = gamma*value + in ----------
// BARRIER-FREE K-loop. Block 256n x 128d, 512 thr, 8 waves; wave = 32 exclusive
// n-rows -> A global->regs directly (named even/odd dbuf). B staged ONCE in LDS
// (128d x 512k f16 = 128KB, XOR-swizzled). One barrier total. Sibling blocks
// {x,x+8,x+16,x+24} = same A rows, dt=0..3, same batch -> same XCD, concurrent
// -> A L2-shared. b = bid&7 == dispatch XCD -> WT L2-resident.
__global__ __launch_bounds__(512, 2) void value_kernel(const float* __restrict__ in,
                                                       const unsigned short* __restrict__ WT,
                                                       const float* __restrict__ gamma,
                                                       float* __restrict__ out) {
    __shared__ unsigned short sB[128 * 512];   // [128 d][512 k] f16, 128 KB, swizzled
    int t = threadIdx.x, lane = t & 63, wave = t >> 6;
    int bid = blockIdx.x;
    int b = bid & 7;
    int dt = (bid >> 3) & 3;
    int nt = bid >> 5;                         // 0..63
    const float* Ain = in + ((size_t)b * NN + (size_t)nt * 256) * C_;
    const unsigned short* Bin = WT + ((size_t)b * C_ + dt * 128) * C_;
    float* outb = out + ((size_t)b * NN + (size_t)nt * 256) * C_;

    // ---- stage B once: 8192 16B-chunks, 16/thread; linear dest, pre-swizzled src ----
#pragma unroll
    for (int i = 0; i < 16; ++i) {
        int chunk = i * 512 + t;
        int o = chunk * 16;
        int row = o >> 10;                     // d-row (1024 B per row)
        int w = o & 1023;
        gload16(Bin + (size_t)row * C_ + ((w ^ ((row & 7) << 4)) >> 1), &sB[chunk * 8]);
    }

    int l15 = lane & 15;
    int g16 = (lane >> 4) * 16;                // k-slot byte offset
    const float* Arow0 = Ain + (size_t)(wave * 32 + l15) * C_ + (lane >> 4) * 8;
    const float* Arow1 = Arow0 + (size_t)16 * C_;

    // preload kt=0 A into even regs
    float4 e0 = *(const float4*)(Arow0 + 0), e1 = *(const float4*)(Arow0 + 4);
    float4 e2 = *(const float4*)(Arow1 + 0), e3 = *(const float4*)(Arow1 + 4);

    asm volatile("s_waitcnt vmcnt(0)" ::: "memory");
    __builtin_amdgcn_s_barrier();              // the ONLY barrier

    f32x4 acc[2][8];
#pragma unroll
    for (int m = 0; m < 2; ++m)
#pragma unroll
        for (int n = 0; n < 8; ++n) acc[m][n] = (f32x4){0.f, 0.f, 0.f, 0.f};

#define CVT_A(aF0, aF1, r0, r1, r2, r3)                                   \
    do {                                                                  \
        const float* f_ = (const float*)&(r0);                            \
        _Pragma("unroll") for (int j = 0; j < 4; ++j) aF0[j] = (_Float16)f_[j]; \
        f_ = (const float*)&(r1);                                         \
        _Pragma("unroll") for (int j = 0; j < 4; ++j) aF0[j + 4] = (_Float16)f_[j]; \
        f_ = (const float*)&(r2);                                         \
        _Pragma("unroll") for (int j = 0; j < 4; ++j) aF1[j] = (_Float16)f_[j]; \
        f_ = (const float*)&(r3);                                         \
        _Pragma("unroll") for (int j = 0; j < 4; ++j) aF1[j + 4] = (_Float16)f_[j]; \
    } while (0)

#define COMPUTE(kt, r0, r1, r2, r3)                                                     \
    do {                                                                                \
        half8 aF0, aF1, bF[8];                                                          \
        CVT_A(aF0, aF1, r0, r1, r2, r3);                                                \
        _Pragma("unroll") for (int n = 0; n < 8; ++n) {                                 \
            int row = n * 16 + l15;                                                     \
            bF[n] = *(const half8*)((const char*)sB +                                   \
                    (row * 1024 + (((kt) * 64 + g16) ^ ((row & 7) << 4))));             \
        }                                                                               \
        _Pragma("unroll") for (int n = 0; n < 8; ++n) {                                 \
            acc[0][n] = __builtin_amdgcn_mfma_f32_16x16x32_f16(aF0, bF[n], acc[0][n], 0, 0, 0); \
            acc[1][n] = __builtin_amdgcn_mfma_f32_16x16x32_f16(aF1, bF[n], acc[1][n], 0, 0, 0); \
        }                                                                               \
    } while (0)

#pragma unroll 1
    for (int it = 0; it < 8; ++it) {
        int kt0 = it * 2;
        // prefetch odd step
        float4 o0 = *(const float4*)(Arow0 + (kt0 + 1) * 32);
        float4 o1 = *(const float4*)(Arow0 + (kt0 + 1) * 32 + 4);
        float4 o2 = *(const float4*)(Arow1 + (kt0 + 1) * 32);
        float4 o3 = *(const float4*)(Arow1 + (kt0 + 1) * 32 + 4);
        COMPUTE(kt0, e0, e1, e2, e3);
        if (it < 7) {
            e0 = *(const float4*)(Arow0 + (kt0 + 2) * 32);
            e1 = *(const float4*)(Arow0 + (kt0 + 2) * 32 + 4);
            e2 = *(const float4*)(Arow1 + (kt0 + 2) * 32);
            e3 = *(const float4*)(Arow1 + (kt0 + 2) * 32 + 4);
        }
        COMPUTE(kt0 + 1, o0, o1, o2, o3);
    }
#undef COMPUTE
#undef CVT_A

    // ---- epilogue: out = gamma*acc + in (in re-read, L2-hot) ----
    float gm = gamma[0];
#pragma unroll
    for (int m = 0; m < 2; ++m) {
        int lr0 = wave * 32 + m * 16 + (lane >> 4) * 4;
#pragma unroll
        for (int n = 0; n < 8; ++n) {
            int dd = dt * 128 + n * 16 + l15;
#pragma unroll
            for (int j = 0; j < 4; ++j) {
                size_t idx = (size_t)(lr0 + j) * C_ + dd;
                outb[idx] = gm * acc[m][n][j] + Ain[idx];
            }
        }
    }
}

// ---------- launch ----------
extern "C" void kernel_launch(void* const* d_in, const int* in_sizes, int n_in,
                              void* d_out, int out_size, void* d_ws, size_t ws_size,
                              hipStream_t stream) {
    const float* in    = (const float*)d_in[0];
    const float* gamma = (const float*)d_in[1];
    float* out = (float*)d_out;

    const size_t q_elems = (size_t)B_ * C_ * NN;                 // 67.1M
    const size_t need = q_elems * 2                              // qT f16
                      + (size_t)SPL * B_ * C_ * C_ * 4           // P partials fp32
                      + (size_t)B_ * C_ * C_ * 2;                // W^T f16
    if (ws_size < need) {   // reveal ws_size via absmax if ever too small
        ws_probe_kernel<<<1, 1, 0, stream>>>(out, (float)ws_size);
        return;
    }

    unsigned short* qT = (unsigned short*)d_ws;
    float* P = (float*)(qT + q_elems);
    unsigned short* WT = (unsigned short*)(P + (size_t)SPL * B_ * C_ * C_);

    pack_kernel<<<dim3(NN / 64, C_ / 64, B_), 256, 0, stream>>>(in, qT);
    gram_kernel<<<256, 512, 0, stream>>>(qT, P);
    softmax_kernel<<<dim3(C_ / 4, B_), 256, 0, stream>>>(P, WT);
    value_kernel<<<2048, 512, 0, stream>>>(in, WT, gamma, out);
}

// Round 9
// 353.980 us; speedup vs baseline: 1.1149x; 1.1149x over previous
//
#include <hip/hip_runtime.h>
#include <hip/hip_bf16.h>

#define B_  8
#define C_  512
#define NN  16384
#define SPL 8
#define KB_ (NN / SPL)   // 2048 per gram block
#define TT  (KB_ / 64)   // 32 K-tiles of 64

typedef _Float16 half8 __attribute__((ext_vector_type(8)));
typedef float    f32x4 __attribute__((ext_vector_type(4)));

__device__ __forceinline__ unsigned short f2h(float x) {
    union { _Float16 h; unsigned short u; } cv;
    cv.h = (_Float16)x;
    return cv.u;
}

__device__ __forceinline__ void gload16(const unsigned short* src, unsigned short* ldst) {
    __builtin_amdgcn_global_load_lds(
        (const __attribute__((address_space(1))) void*)src,
        (__attribute__((address_space(3))) void*)ldst,
        16, 0, 0);
}

__global__ void ws_probe_kernel(float* out, float v) { out[0] = v; }

// ---------- kernel 1: pack fp32 [b][n][c] -> qT f16 [b][c][n] + qn f16 [b][n][c] ----------
__global__ __launch_bounds__(256) void pack_kernel(const float* __restrict__ in,
                                                   unsigned short* __restrict__ qT,
                                                   unsigned short* __restrict__ qn) {
    __shared__ unsigned short lh[64][72];
    int t  = threadIdx.x;
    int n0 = blockIdx.x * 64;
    int c0 = blockIdx.y * 64;
    int b  = blockIdx.z;
    const float* ib = in + ((size_t)b * NN + n0) * C_ + c0;
#pragma unroll
    for (int p = 0; p < 4; ++p) {
        int nl = p * 16 + (t >> 4);
        int cl = (t & 15) * 4;
        float4 v = *(const float4*)(ib + (size_t)nl * C_ + cl);
        ushort4 q4;
        q4.x = f2h(v.x); q4.y = f2h(v.y); q4.z = f2h(v.z); q4.w = f2h(v.w);
        lh[cl + 0][nl] = q4.x;
        lh[cl + 1][nl] = q4.y;
        lh[cl + 2][nl] = q4.z;
        lh[cl + 3][nl] = q4.w;
        *(ushort4*)(qn + ((size_t)b * NN + n0 + nl) * C_ + c0 + cl) = q4;
    }
    __syncthreads();
    size_t obase = ((size_t)b * C_ + c0) * NN + n0;
#pragma unroll
    for (int p = 0; p < 2; ++p) {
        int cr = p * 32 + (t >> 3);
        int nf = (t & 7) * 8;
        *(uint4*)(qT + obase + (size_t)cr * NN + nf) = *(const uint4*)&lh[cr][nf];
    }
}

// ---------- kernel 2: Gram, 256x256 tile, BK=64, pipelined; atomic split-sum ----------
// grid 256: b = bid&7 (XCD locality), r=bid>>3: tile=r&3 (tc,td), split=r>>2
// P layout: [b][512][512] fp32, pre-zeroed; partials accumulated via HW fp32 atomics.
__global__ __launch_bounds__(512, 2) void gram_kernel(const unsigned short* __restrict__ qT,
                                                      float* __restrict__ P) {
    __shared__ unsigned short sA[2][16384];
    __shared__ unsigned short sB[2][16384];
    int t = threadIdx.x, lane = t & 63, wave = t >> 6;
    int wr = wave >> 2, wc = wave & 3;           // 2 x 4 wave grid
    int bid = blockIdx.x;
    int b = bid & 7, r = bid >> 3;
    int tile = r & 3, split = r >> 2;
    int tc = tile >> 1, td = tile & 1;
    size_t qb = (size_t)b * C_ * NN;
    const unsigned short* Ap = qT + qb + (size_t)(tc * 256) * NN + (size_t)split * KB_;
    const unsigned short* Bp = qT + qb + (size_t)(td * 256) * NN + (size_t)split * KB_;

    f32x4 acc[8][4];
#pragma unroll
    for (int m = 0; m < 8; ++m)
#pragma unroll
        for (int n = 0; n < 4; ++n) acc[m][n] = (f32x4){0.f, 0.f, 0.f, 0.f};

    int o0 = t * 16,         u0 = o0 ^ (((o0 >> 9) & 1) << 5);
    int o1 = (t + 512) * 16, u1 = o1 ^ (((o1 >> 9) & 1) << 5);
    int rih0 = u0 >> 7, k0 = (u0 & 127) >> 1;
    int rih1 = u1 >> 7, k1 = (u1 & 127) >> 1;

#define STAGE(dst, dd, h, panel, kt)                                                        \
    do {                                                                                    \
        gload16((panel) + (size_t)((h)*128 + rih0) * NN + (kt)*64 + k0,                     \
                &dst[dd][(h)*8192 + t * 8]);                                                \
        gload16((panel) + (size_t)((h)*128 + rih1) * NN + (kt)*64 + k1,                     \
                &dst[dd][(h)*8192 + (t + 512) * 8]);                                        \
    } while (0)

    int g16 = (lane >> 4) * 16;
#define AFRAG(dd, row, ks) \
    (*(const half8*)((const char*)&sA[dd][0] + (((row)*128 + (ks)*64 + g16) ^ (((row)&4) << 3))))
#define BFRAG(dd, row, ks) \
    (*(const half8*)((const char*)&sB[dd][0] + (((row)*128 + (ks)*64 + g16) ^ (((row)&4) << 3))))

    STAGE(sA, 0, 0, Ap, 0);
    STAGE(sB, 0, 0, Bp, 0);
    STAGE(sB, 0, 1, Bp, 0);
    STAGE(sA, 0, 1, Ap, 0);
    asm volatile("s_waitcnt vmcnt(2)" ::: "memory");
    __builtin_amdgcn_s_barrier();

    for (int kt = 0; kt < TT; ++kt) {
        int d = kt & 1, nd = d ^ 1;
        half8 aF[4][2], b0F[2][2], b1F[2][2];
#pragma unroll
        for (int m = 0; m < 4; ++m) {
            int row = wr * 64 + m * 16 + (lane & 15);
#pragma unroll
            for (int ks = 0; ks < 2; ++ks) aF[m][ks] = AFRAG(d, row, ks);
        }
#pragma unroll
        for (int n = 0; n < 2; ++n) {
            int row0 = wc * 32 + n * 16 + (lane & 15);
#pragma unroll
            for (int ks = 0; ks < 2; ++ks) {
                b0F[n][ks] = BFRAG(d, row0, ks);
                b1F[n][ks] = BFRAG(d, (row0 + 128), ks);
            }
        }
        if (kt + 1 < TT) {
            STAGE(sA, nd, 0, Ap, kt + 1);
            STAGE(sB, nd, 0, Bp, kt + 1);
            STAGE(sB, nd, 1, Bp, kt + 1);
        }
        __builtin_amdgcn_s_setprio(1);
#pragma unroll
        for (int m = 0; m < 4; ++m)
#pragma unroll
            for (int n = 0; n < 2; ++n)
#pragma unroll
                for (int ks = 0; ks < 2; ++ks) {
                    acc[m][n]     = __builtin_amdgcn_mfma_f32_16x16x32_f16(aF[m][ks], b0F[n][ks], acc[m][n],     0, 0, 0);
                    acc[m][n + 2] = __builtin_amdgcn_mfma_f32_16x16x32_f16(aF[m][ks], b1F[n][ks], acc[m][n + 2], 0, 0, 0);
                }
        __builtin_amdgcn_s_setprio(0);
        if (kt + 1 < TT) {
            asm volatile("s_waitcnt vmcnt(6)" ::: "memory");
        } else {
            asm volatile("s_waitcnt vmcnt(0)" ::: "memory");
        }
        __builtin_amdgcn_s_barrier();
#pragma unroll
        for (int m = 0; m < 4; ++m) {
            int row = 128 + wr * 64 + m * 16 + (lane & 15);
#pragma unroll
            for (int ks = 0; ks < 2; ++ks) aF[m][ks] = AFRAG(d, row, ks);
        }
        if (kt + 1 < TT) STAGE(sA, nd, 1, Ap, kt + 1);
        __builtin_amdgcn_s_setprio(1);
#pragma unroll
        for (int m = 0; m < 4; ++m)
#pragma unroll
            for (int n = 0; n < 2; ++n)
#pragma unroll
                for (int ks = 0; ks < 2; ++ks) {
                    acc[m + 4][n + 2] = __builtin_amdgcn_mfma_f32_16x16x32_f16(aF[m][ks], b1F[n][ks], acc[m + 4][n + 2], 0, 0, 0);
                    acc[m + 4][n]     = __builtin_amdgcn_mfma_f32_16x16x32_f16(aF[m][ks], b0F[n][ks], acc[m + 4][n],     0, 0, 0);
                }
        __builtin_amdgcn_s_setprio(0);
        asm volatile("s_waitcnt vmcnt(2)" ::: "memory");
        __builtin_amdgcn_s_barrier();
    }

    float* outp = P + (size_t)b * (C_ * C_);
#pragma unroll
    for (int m = 0; m < 8; ++m) {
        int row0 = tc * 256 + wr * 64 + (m & 3) * 16 + (m >> 2) * 128 + (lane >> 4) * 4;
#pragma unroll
        for (int n = 0; n < 4; ++n) {
            int col = td * 256 + wc * 32 + (n & 1) * 16 + (n >> 1) * 128 + (lane & 15);
#pragma unroll
            for (int j = 0; j < 4; ++j)
                unsafeAtomicAdd(&outp[(size_t)(row0 + j) * C_ + col], acc[m][n][j]);
        }
    }
#undef STAGE
#undef AFRAG
#undef BFRAG
}

// ---------- kernel 3: reversed softmax on P -> W^T f16 [b][d][c] ----------
__global__ __launch_bounds__(256) void softmax_kernel(const float* __restrict__ P,
                                                      unsigned short* __restrict__ WT) {
    __shared__ unsigned short lw[C_ * 4];
    int t = threadIdx.x, lane = t & 63, wave = t >> 6;
    int b = blockIdx.y;
    int c = blockIdx.x * 4 + wave;
    const float* base = P + (size_t)b * (C_ * C_) + (size_t)c * C_;

    float g[8];
    float mn = 3.4e38f;
#pragma unroll
    for (int k = 0; k < 8; ++k) {
        int d = k * 64 + lane;
        float v = base[d];
        g[k] = v;
        mn = fminf(mn, v);
    }
#pragma unroll
    for (int o = 32; o; o >>= 1) mn = fminf(mn, __shfl_xor(mn, o));
    float w[8];
    float sum = 0.f;
#pragma unroll
    for (int k = 0; k < 8; ++k) { w[k] = __expf(mn - g[k]); sum += w[k]; }
#pragma unroll
    for (int o = 32; o; o >>= 1) sum += __shfl_xor(sum, o);
    float inv = 1.0f / sum;
#pragma unroll
    for (int k = 0; k < 8; ++k) {
        int d = k * 64 + lane;
        lw[d * 4 + wave] = f2h(w[k] * inv);
    }
    __syncthreads();
    int c0 = blockIdx.x * 4;
    for (int d = t; d < C_; d += 256)
        *(ushort4*)(WT + ((size_t)b * C_ + d) * C_ + c0) = *(ushort4*)&lw[d * 4];
}

// ---------- kernel 4: value = qn @ W^T, out = gamma*value + in  (GRAM CLONE) ----------
// grid 1024: b = bid&7, r = bid>>3: dt = r&1 (d half), nt = r>>1 (n tile).
// A = qn rows [nt*256 .. +256) (f16, k=c contiguous); B = WT rows [dt*256..) (L2).
// Same tile/schedule/swizzles as gram_kernel; K = 512 -> 8 steps.
// Epilogue: out = gamma*acc + f16(in) (qn re-read, L2-hot from own staging).
__global__ __launch_bounds__(512, 2) void value_kernel(const unsigned short* __restrict__ qn,
                                                       const unsigned short* __restrict__ WT,
                                                       const float* __restrict__ gamma,
                                                       float* __restrict__ out) {
    __shared__ unsigned short sA[2][16384];
    __shared__ unsigned short sB[2][16384];
    int t = threadIdx.x, lane = t & 63, wave = t >> 6;
    int wr = wave >> 2, wc = wave & 3;
    int bid = blockIdx.x;
    int b = bid & 7, r = bid >> 3;
    int dt = r & 1, nt = r >> 1;
    const unsigned short* Ap = qn + ((size_t)b * NN + (size_t)nt * 256) * C_;
    const unsigned short* Bp = WT + ((size_t)b * C_ + dt * 256) * C_;

    f32x4 acc[8][4];
#pragma unroll
    for (int m = 0; m < 8; ++m)
#pragma unroll
        for (int n = 0; n < 4; ++n) acc[m][n] = (f32x4){0.f, 0.f, 0.f, 0.f};

    int o0 = t * 16,         u0 = o0 ^ (((o0 >> 9) & 1) << 5);
    int o1 = (t + 512) * 16, u1 = o1 ^ (((o1 >> 9) & 1) << 5);
    int rih0 = u0 >> 7, k0 = (u0 & 127) >> 1;
    int rih1 = u1 >> 7, k1 = (u1 & 127) >> 1;

#define STAGE(dst, dd, h, panel, kt)                                                        \
    do {                                                                                    \
        gload16((panel) + (size_t)((h)*128 + rih0) * C_ + (kt)*64 + k0,                     \
                &dst[dd][(h)*8192 + t * 8]);                                                \
        gload16((panel) + (size_t)((h)*128 + rih1) * C_ + (kt)*64 + k1,                     \
                &dst[dd][(h)*8192 + (t + 512) * 8]);                                        \
    } while (0)

    int g16 = (lane >> 4) * 16;
#define AFRAG(dd, row, ks) \
    (*(const half8*)((const char*)&sA[dd][0] + (((row)*128 + (ks)*64 + g16) ^ (((row)&4) << 3))))
#define BFRAG(dd, row, ks) \
    (*(const half8*)((const char*)&sB[dd][0] + (((row)*128 + (ks)*64 + g16) ^ (((row)&4) << 3))))

    STAGE(sA, 0, 0, Ap, 0);
    STAGE(sB, 0, 0, Bp, 0);
    STAGE(sB, 0, 1, Bp, 0);
    STAGE(sA, 0, 1, Ap, 0);
    asm volatile("s_waitcnt vmcnt(2)" ::: "memory");
    __builtin_amdgcn_s_barrier();

    for (int kt = 0; kt < 8; ++kt) {
        int d = kt & 1, nd = d ^ 1;
        half8 aF[4][2], b0F[2][2], b1F[2][2];
#pragma unroll
        for (int m = 0; m < 4; ++m) {
            int row = wr * 64 + m * 16 + (lane & 15);
#pragma unroll
            for (int ks = 0; ks < 2; ++ks) aF[m][ks] = AFRAG(d, row, ks);
        }
#pragma unroll
        for (int n = 0; n < 2; ++n) {
            int row0 = wc * 32 + n * 16 + (lane & 15);
#pragma unroll
            for (int ks = 0; ks < 2; ++ks) {
                b0F[n][ks] = BFRAG(d, row0, ks);
                b1F[n][ks] = BFRAG(d, (row0 + 128), ks);
            }
        }
        if (kt + 1 < 8) {
            STAGE(sA, nd, 0, Ap, kt + 1);
            STAGE(sB, nd, 0, Bp, kt + 1);
            STAGE(sB, nd, 1, Bp, kt + 1);
        }
        __builtin_amdgcn_s_setprio(1);
#pragma unroll
        for (int m = 0; m < 4; ++m)
#pragma unroll
            for (int n = 0; n < 2; ++n)
#pragma unroll
                for (int ks = 0; ks < 2; ++ks) {
                    acc[m][n]     = __builtin_amdgcn_mfma_f32_16x16x32_f16(aF[m][ks], b0F[n][ks], acc[m][n],     0, 0, 0);
                    acc[m][n + 2] = __builtin_amdgcn_mfma_f32_16x16x32_f16(aF[m][ks], b1F[n][ks], acc[m][n + 2], 0, 0, 0);
                }
        __builtin_amdgcn_s_setprio(0);
        if (kt + 1 < 8) {
            asm volatile("s_waitcnt vmcnt(6)" ::: "memory");
        } else {
            asm volatile("s_waitcnt vmcnt(0)" ::: "memory");
        }
        __builtin_amdgcn_s_barrier();
#pragma unroll
        for (int m = 0; m < 4; ++m) {
            int row = 128 + wr * 64 + m * 16 + (lane & 15);
#pragma unroll
            for (int ks = 0; ks < 2; ++ks) aF[m][ks] = AFRAG(d, row, ks);
        }
        if (kt + 1 < 8) STAGE(sA, nd, 1, Ap, kt + 1);
        __builtin_amdgcn_s_setprio(1);
#pragma unroll
        for (int m = 0; m < 4; ++m)
#pragma unroll
            for (int n = 0; n < 2; ++n)
#pragma unroll
                for (int ks = 0; ks < 2; ++ks) {
                    acc[m + 4][n + 2] = __builtin_amdgcn_mfma_f32_16x16x32_f16(aF[m][ks], b1F[n][ks], acc[m + 4][n + 2], 0, 0, 0);
                    acc[m + 4][n]     = __builtin_amdgcn_mfma_f32_16x16x32_f16(aF[m][ks], b0F[n][ks], acc[m + 4][n],     0, 0, 0);
                }
        __builtin_amdgcn_s_setprio(0);
        asm volatile("s_waitcnt vmcnt(2)" ::: "memory");
        __builtin_amdgcn_s_barrier();
    }

    float gm = gamma[0];
#pragma unroll
    for (int m = 0; m < 8; ++m) {
        int row0 = nt * 256 + wr * 64 + (m & 3) * 16 + (m >> 2) * 128 + (lane >> 4) * 4;
#pragma unroll
        for (int n = 0; n < 4; ++n) {
            int col = dt * 256 + wc * 32 + (n & 1) * 16 + (n >> 1) * 128 + (lane & 15);
#pragma unroll
            for (int j = 0; j < 4; ++j) {
                size_t idx = ((size_t)b * NN + (row0 + j)) * C_ + col;
                float iv = (float)(*(const _Float16*)&qn[idx]);
                out[idx] = gm * acc[m][n][j] + iv;
            }
        }
    }
#undef STAGE
#undef AFRAG
#undef BFRAG
}

// ---------- launch ----------
extern "C" void kernel_launch(void* const* d_in, const int* in_sizes, int n_in,
                              void* d_out, int out_size, void* d_ws, size_t ws_size,
                              hipStream_t stream) {
    const float* in    = (const float*)d_in[0];
    const float* gamma = (const float*)d_in[1];
    float* out = (float*)d_out;

    const size_t q_elems = (size_t)B_ * C_ * NN;                 // 67.1M
    const size_t p_elems = (size_t)B_ * C_ * C_;                 // 2.1M
    const size_t need = q_elems * 2                              // qT f16
                      + q_elems * 2                              // qn f16
                      + p_elems * 4                              // P fp32 (single)
                      + p_elems * 2;                             // W^T f16
    if (ws_size < need) {   // reveal ws_size via absmax if ever too small
        ws_probe_kernel<<<1, 1, 0, stream>>>(out, (float)ws_size);
        return;
    }

    unsigned short* qT = (unsigned short*)d_ws;
    unsigned short* qn = qT + q_elems;
    float* P = (float*)(qn + q_elems);
    unsigned short* WT = (unsigned short*)(P + p_elems);

    hipMemsetAsync(P, 0, p_elems * 4, stream);
    pack_kernel<<<dim3(NN / 64, C_ / 64, B_), 256, 0, stream>>>(in, qT, qn);
    gram_kernel<<<256, 512, 0, stream>>>(qT, P);
    softmax_kernel<<<dim3(C_ / 4, B_), 256, 0, stream>>>(P, WT);
    value_kernel<<<1024, 512, 0, stream>>>(qn, WT, gamma, out);
}

// Round 10
// 339.695 us; speedup vs baseline: 1.1618x; 1.0421x over previous
//
#include <hip/hip_runtime.h>
#include <hip/hip_bf16.h>

#define B_  8
#define C_  512
#define NN  16384
#define SPL 8
#define KB_ (NN / SPL)   // 2048 per gram block
#define TT  (KB_ / 64)   // 32 K-tiles of 64

typedef _Float16 half8 __attribute__((ext_vector_type(8)));
typedef float    f32x4 __attribute__((ext_vector_type(4)));

__device__ __forceinline__ unsigned short f2h(float x) {
    union { _Float16 h; unsigned short u; } cv;
    cv.h = (_Float16)x;
    return cv.u;
}

__device__ __forceinline__ void gload16(const unsigned short* src, unsigned short* ldst) {
    __builtin_amdgcn_global_load_lds(
        (const __attribute__((address_space(1))) void*)src,
        (__attribute__((address_space(3))) void*)ldst,
        16, 0, 0);
}

__global__ void ws_probe_kernel(float* out, float v) { out[0] = v; }

// ---------- kernel 1: pack fp32 [b][n][c] -> qT f16 [b][c][n] + qn f16 [b][n][c] ----------
__global__ __launch_bounds__(256) void pack_kernel(const float* __restrict__ in,
                                                   unsigned short* __restrict__ qT,
                                                   unsigned short* __restrict__ qn) {
    __shared__ unsigned short lh[64][72];
    int t  = threadIdx.x;
    int n0 = blockIdx.x * 64;
    int c0 = blockIdx.y * 64;
    int b  = blockIdx.z;
    const float* ib = in + ((size_t)b * NN + n0) * C_ + c0;
#pragma unroll
    for (int p = 0; p < 4; ++p) {
        int nl = p * 16 + (t >> 4);
        int cl = (t & 15) * 4;
        float4 v = *(const float4*)(ib + (size_t)nl * C_ + cl);
        ushort4 q4;
        q4.x = f2h(v.x); q4.y = f2h(v.y); q4.z = f2h(v.z); q4.w = f2h(v.w);
        lh[cl + 0][nl] = q4.x;
        lh[cl + 1][nl] = q4.y;
        lh[cl + 2][nl] = q4.z;
        lh[cl + 3][nl] = q4.w;
        *(ushort4*)(qn + ((size_t)b * NN + n0 + nl) * C_ + c0 + cl) = q4;
    }
    __syncthreads();
    size_t obase = ((size_t)b * C_ + c0) * NN + n0;
#pragma unroll
    for (int p = 0; p < 2; ++p) {
        int cr = p * 32 + (t >> 3);
        int nf = (t & 7) * 8;
        *(uint4*)(qT + obase + (size_t)cr * NN + nf) = *(const uint4*)&lh[cr][nf];
    }
}

// ---------- kernel 2: Gram partials, 256x256 tile, BK=64, pipelined ----------
// grid 256: b = bid&7 (XCD locality), r=bid>>3: tile=r&3 (tc,td), split=r>>2
// P layout: [split(8)][b][512][512] fp32 (plain stores, no zeroing needed)
__global__ __launch_bounds__(512, 2) void gram_kernel(const unsigned short* __restrict__ qT,
                                                      float* __restrict__ P) {
    __shared__ unsigned short sA[2][16384];
    __shared__ unsigned short sB[2][16384];
    int t = threadIdx.x, lane = t & 63, wave = t >> 6;
    int wr = wave >> 2, wc = wave & 3;           // 2 x 4 wave grid
    int bid = blockIdx.x;
    int b = bid & 7, r = bid >> 3;
    int tile = r & 3, split = r >> 2;
    int tc = tile >> 1, td = tile & 1;
    size_t qb = (size_t)b * C_ * NN;
    const unsigned short* Ap = qT + qb + (size_t)(tc * 256) * NN + (size_t)split * KB_;
    const unsigned short* Bp = qT + qb + (size_t)(td * 256) * NN + (size_t)split * KB_;

    f32x4 acc[8][4];
#pragma unroll
    for (int m = 0; m < 8; ++m)
#pragma unroll
        for (int n = 0; n < 4; ++n) acc[m][n] = (f32x4){0.f, 0.f, 0.f, 0.f};

    int o0 = t * 16,         u0 = o0 ^ (((o0 >> 9) & 1) << 5);
    int o1 = (t + 512) * 16, u1 = o1 ^ (((o1 >> 9) & 1) << 5);
    int rih0 = u0 >> 7, k0 = (u0 & 127) >> 1;
    int rih1 = u1 >> 7, k1 = (u1 & 127) >> 1;

#define STAGE(dst, dd, h, panel, kt)                                                        \
    do {                                                                                    \
        gload16((panel) + (size_t)((h)*128 + rih0) * NN + (kt)*64 + k0,                     \
                &dst[dd][(h)*8192 + t * 8]);                                                \
        gload16((panel) + (size_t)((h)*128 + rih1) * NN + (kt)*64 + k1,                     \
                &dst[dd][(h)*8192 + (t + 512) * 8]);                                        \
    } while (0)

    int g16 = (lane >> 4) * 16;
#define AFRAG(dd, row, ks) \
    (*(const half8*)((const char*)&sA[dd][0] + (((row)*128 + (ks)*64 + g16) ^ (((row)&4) << 3))))
#define BFRAG(dd, row, ks) \
    (*(const half8*)((const char*)&sB[dd][0] + (((row)*128 + (ks)*64 + g16) ^ (((row)&4) << 3))))

    STAGE(sA, 0, 0, Ap, 0);
    STAGE(sB, 0, 0, Bp, 0);
    STAGE(sB, 0, 1, Bp, 0);
    STAGE(sA, 0, 1, Ap, 0);
    asm volatile("s_waitcnt vmcnt(2)" ::: "memory");
    __builtin_amdgcn_s_barrier();

    for (int kt = 0; kt < TT; ++kt) {
        int d = kt & 1, nd = d ^ 1;
        half8 aF[4][2], b0F[2][2], b1F[2][2];
#pragma unroll
        for (int m = 0; m < 4; ++m) {
            int row = wr * 64 + m * 16 + (lane & 15);
#pragma unroll
            for (int ks = 0; ks < 2; ++ks) aF[m][ks] = AFRAG(d, row, ks);
        }
#pragma unroll
        for (int n = 0; n < 2; ++n) {
            int row0 = wc * 32 + n * 16 + (lane & 15);
#pragma unroll
            for (int ks = 0; ks < 2; ++ks) {
                b0F[n][ks] = BFRAG(d, row0, ks);
                b1F[n][ks] = BFRAG(d, (row0 + 128), ks);
            }
        }
        if (kt + 1 < TT) {
            STAGE(sA, nd, 0, Ap, kt + 1);
            STAGE(sB, nd, 0, Bp, kt + 1);
            STAGE(sB, nd, 1, Bp, kt + 1);
        }
        __builtin_amdgcn_s_setprio(1);
#pragma unroll
        for (int m = 0; m < 4; ++m)
#pragma unroll
            for (int n = 0; n < 2; ++n)
#pragma unroll
                for (int ks = 0; ks < 2; ++ks) {
                    acc[m][n]     = __builtin_amdgcn_mfma_f32_16x16x32_f16(aF[m][ks], b0F[n][ks], acc[m][n],     0, 0, 0);
                    acc[m][n + 2] = __builtin_amdgcn_mfma_f32_16x16x32_f16(aF[m][ks], b1F[n][ks], acc[m][n + 2], 0, 0, 0);
                }
        __builtin_amdgcn_s_setprio(0);
        if (kt + 1 < TT) {
            asm volatile("s_waitcnt vmcnt(6)" ::: "memory");
        } else {
            asm volatile("s_waitcnt vmcnt(0)" ::: "memory");
        }
        __builtin_amdgcn_s_barrier();
#pragma unroll
        for (int m = 0; m < 4; ++m) {
            int row = 128 + wr * 64 + m * 16 + (lane & 15);
#pragma unroll
            for (int ks = 0; ks < 2; ++ks) aF[m][ks] = AFRAG(d, row, ks);
        }
        if (kt + 1 < TT) STAGE(sA, nd, 1, Ap, kt + 1);
        __builtin_amdgcn_s_setprio(1);
#pragma unroll
        for (int m = 0; m < 4; ++m)
#pragma unroll
            for (int n = 0; n < 2; ++n)
#pragma unroll
                for (int ks = 0; ks < 2; ++ks) {
                    acc[m + 4][n + 2] = __builtin_amdgcn_mfma_f32_16x16x32_f16(aF[m][ks], b1F[n][ks], acc[m + 4][n + 2], 0, 0, 0);
                    acc[m + 4][n]     = __builtin_amdgcn_mfma_f32_16x16x32_f16(aF[m][ks], b0F[n][ks], acc[m + 4][n],     0, 0, 0);
                }
        __builtin_amdgcn_s_setprio(0);
        asm volatile("s_waitcnt vmcnt(2)" ::: "memory");
        __builtin_amdgcn_s_barrier();
    }

    float* outp = P + ((size_t)(split * 8 + b)) * (C_ * C_);
#pragma unroll
    for (int m = 0; m < 8; ++m) {
        int row0 = tc * 256 + wr * 64 + (m & 3) * 16 + (m >> 2) * 128 + (lane >> 4) * 4;
#pragma unroll
        for (int n = 0; n < 4; ++n) {
            int col = td * 256 + wc * 32 + (n & 1) * 16 + (n >> 1) * 128 + (lane & 15);
#pragma unroll
            for (int j = 0; j < 4; ++j)
                outp[(size_t)(row0 + j) * C_ + col] = acc[m][n][j];
        }
    }
#undef STAGE
#undef AFRAG
#undef BFRAG
}

// ---------- kernel 3: sum splits + reversed softmax -> W^T f16 [b][d][c] ----------
__global__ __launch_bounds__(256) void softmax_kernel(const float* __restrict__ P,
                                                      unsigned short* __restrict__ WT) {
    __shared__ unsigned short lw[C_ * 4];
    int t = threadIdx.x, lane = t & 63, wave = t >> 6;
    int b = blockIdx.y;
    int c = blockIdx.x * 4 + wave;
    const float* base = P + (size_t)b * (C_ * C_) + (size_t)c * C_;

    float g[8];
    float mn = 3.4e38f;
#pragma unroll
    for (int k = 0; k < 8; ++k) {
        int d = k * 64 + lane;
        float v = 0.f;
#pragma unroll
        for (int s = 0; s < 8; ++s) v += base[(size_t)s * (8 * C_ * C_) + d];
        g[k] = v;
        mn = fminf(mn, v);
    }
#pragma unroll
    for (int o = 32; o; o >>= 1) mn = fminf(mn, __shfl_xor(mn, o));
    float w[8];
    float sum = 0.f;
#pragma unroll
    for (int k = 0; k < 8; ++k) { w[k] = __expf(mn - g[k]); sum += w[k]; }
#pragma unroll
    for (int o = 32; o; o >>= 1) sum += __shfl_xor(sum, o);
    float inv = 1.0f / sum;
#pragma unroll
    for (int k = 0; k < 8; ++k) {
        int d = k * 64 + lane;
        lw[d * 4 + wave] = f2h(w[k] * inv);
    }
    __syncthreads();
    int c0 = blockIdx.x * 4;
    for (int d = t; d < C_; d += 256)
        *(ushort4*)(WT + ((size_t)b * C_ + d) * C_ + c0) = *(ushort4*)&lw[d * 4];
}

// ---------- kernel 4: value = qn @ W^T, out = gamma*value + in  (GRAM CLONE) ----------
// grid 1024: b = bid&7, r = bid>>3: dt = r&1 (d half), nt = r>>1 (n tile).
// A = qn rows (f16, k=c contiguous); B = WT rows (L2). K = 512 -> 8 steps.
// Epilogue: out = gamma*acc + f16(in) (qn re-read, L2-hot).
__global__ __launch_bounds__(512, 2) void value_kernel(const unsigned short* __restrict__ qn,
                                                       const unsigned short* __restrict__ WT,
                                                       const float* __restrict__ gamma,
                                                       float* __restrict__ out) {
    __shared__ unsigned short sA[2][16384];
    __shared__ unsigned short sB[2][16384];
    int t = threadIdx.x, lane = t & 63, wave = t >> 6;
    int wr = wave >> 2, wc = wave & 3;
    int bid = blockIdx.x;
    int b = bid & 7, r = bid >> 3;
    int dt = r & 1, nt = r >> 1;
    const unsigned short* Ap = qn + ((size_t)b * NN + (size_t)nt * 256) * C_;
    const unsigned short* Bp = WT + ((size_t)b * C_ + dt * 256) * C_;

    f32x4 acc[8][4];
#pragma unroll
    for (int m = 0; m < 8; ++m)
#pragma unroll
        for (int n = 0; n < 4; ++n) acc[m][n] = (f32x4){0.f, 0.f, 0.f, 0.f};

    int o0 = t * 16,         u0 = o0 ^ (((o0 >> 9) & 1) << 5);
    int o1 = (t + 512) * 16, u1 = o1 ^ (((o1 >> 9) & 1) << 5);
    int rih0 = u0 >> 7, k0 = (u0 & 127) >> 1;
    int rih1 = u1 >> 7, k1 = (u1 & 127) >> 1;

#define STAGE(dst, dd, h, panel, kt)                                                        \
    do {                                                                                    \
        gload16((panel) + (size_t)((h)*128 + rih0) * C_ + (kt)*64 + k0,                     \
                &dst[dd][(h)*8192 + t * 8]);                                                \
        gload16((panel) + (size_t)((h)*128 + rih1) * C_ + (kt)*64 + k1,                     \
                &dst[dd][(h)*8192 + (t + 512) * 8]);                                        \
    } while (0)

    int g16 = (lane >> 4) * 16;
#define AFRAG(dd, row, ks) \
    (*(const half8*)((const char*)&sA[dd][0] + (((row)*128 + (ks)*64 + g16) ^ (((row)&4) << 3))))
#define BFRAG(dd, row, ks) \
    (*(const half8*)((const char*)&sB[dd][0] + (((row)*128 + (ks)*64 + g16) ^ (((row)&4) << 3))))

    STAGE(sA, 0, 0, Ap, 0);
    STAGE(sB, 0, 0, Bp, 0);
    STAGE(sB, 0, 1, Bp, 0);
    STAGE(sA, 0, 1, Ap, 0);
    asm volatile("s_waitcnt vmcnt(2)" ::: "memory");
    __builtin_amdgcn_s_barrier();

    for (int kt = 0; kt < 8; ++kt) {
        int d = kt & 1, nd = d ^ 1;
        half8 aF[4][2], b0F[2][2], b1F[2][2];
#pragma unroll
        for (int m = 0; m < 4; ++m) {
            int row = wr * 64 + m * 16 + (lane & 15);
#pragma unroll
            for (int ks = 0; ks < 2; ++ks) aF[m][ks] = AFRAG(d, row, ks);
        }
#pragma unroll
        for (int n = 0; n < 2; ++n) {
            int row0 = wc * 32 + n * 16 + (lane & 15);
#pragma unroll
            for (int ks = 0; ks < 2; ++ks) {
                b0F[n][ks] = BFRAG(d, row0, ks);
                b1F[n][ks] = BFRAG(d, (row0 + 128), ks);
            }
        }
        if (kt + 1 < 8) {
            STAGE(sA, nd, 0, Ap, kt + 1);
            STAGE(sB, nd, 0, Bp, kt + 1);
            STAGE(sB, nd, 1, Bp, kt + 1);
        }
        __builtin_amdgcn_s_setprio(1);
#pragma unroll
        for (int m = 0; m < 4; ++m)
#pragma unroll
            for (int n = 0; n < 2; ++n)
#pragma unroll
                for (int ks = 0; ks < 2; ++ks) {
                    acc[m][n]     = __builtin_amdgcn_mfma_f32_16x16x32_f16(aF[m][ks], b0F[n][ks], acc[m][n],     0, 0, 0);
                    acc[m][n + 2] = __builtin_amdgcn_mfma_f32_16x16x32_f16(aF[m][ks], b1F[n][ks], acc[m][n + 2], 0, 0, 0);
                }
        __builtin_amdgcn_s_setprio(0);
        if (kt + 1 < 8) {
            asm volatile("s_waitcnt vmcnt(6)" ::: "memory");
        } else {
            asm volatile("s_waitcnt vmcnt(0)" ::: "memory");
        }
        __builtin_amdgcn_s_barrier();
#pragma unroll
        for (int m = 0; m < 4; ++m) {
            int row = 128 + wr * 64 + m * 16 + (lane & 15);
#pragma unroll
            for (int ks = 0; ks < 2; ++ks) aF[m][ks] = AFRAG(d, row, ks);
        }
        if (kt + 1 < 8) STAGE(sA, nd, 1, Ap, kt + 1);
        __builtin_amdgcn_s_setprio(1);
#pragma unroll
        for (int m = 0; m < 4; ++m)
#pragma unroll
            for (int n = 0; n < 2; ++n)
#pragma unroll
                for (int ks = 0; ks < 2; ++ks) {
                    acc[m + 4][n + 2] = __builtin_amdgcn_mfma_f32_16x16x32_f16(aF[m][ks], b1F[n][ks], acc[m + 4][n + 2], 0, 0, 0);
                    acc[m + 4][n]     = __builtin_amdgcn_mfma_f32_16x16x32_f16(aF[m][ks], b0F[n][ks], acc[m + 4][n],     0, 0, 0);
                }
        __builtin_amdgcn_s_setprio(0);
        asm volatile("s_waitcnt vmcnt(2)" ::: "memory");
        __builtin_amdgcn_s_barrier();
    }

    float gm = gamma[0];
#pragma unroll
    for (int m = 0; m < 8; ++m) {
        int row0 = nt * 256 + wr * 64 + (m & 3) * 16 + (m >> 2) * 128 + (lane >> 4) * 4;
#pragma unroll
        for (int n = 0; n < 4; ++n) {
            int col = dt * 256 + wc * 32 + (n & 1) * 16 + (n >> 1) * 128 + (lane & 15);
#pragma unroll
            for (int j = 0; j < 4; ++j) {
                size_t idx = ((size_t)b * NN + (row0 + j)) * C_ + col;
                float iv = (float)(*(const _Float16*)&qn[idx]);
                out[idx] = gm * acc[m][n][j] + iv;
            }
        }
    }
#undef STAGE
#undef AFRAG
#undef BFRAG
}

// ---------- launch ----------
extern "C" void kernel_launch(void* const* d_in, const int* in_sizes, int n_in,
                              void* d_out, int out_size, void* d_ws, size_t ws_size,
                              hipStream_t stream) {
    const float* in    = (const float*)d_in[0];
    const float* gamma = (const float*)d_in[1];
    float* out = (float*)d_out;

    const size_t q_elems = (size_t)B_ * C_ * NN;                 // 67.1M
    const size_t p_elems = (size_t)B_ * C_ * C_;                 // 2.1M
    const size_t need = q_elems * 2                              // qT f16
                      + q_elems * 2                              // qn f16
                      + (size_t)SPL * p_elems * 4                // P partials fp32
                      + p_elems * 2;                             // W^T f16
    if (ws_size < need) {   // reveal ws_size via absmax if ever too small
        ws_probe_kernel<<<1, 1, 0, stream>>>(out, (float)ws_size);
        return;
    }

    unsigned short* qT = (unsigned short*)d_ws;
    unsigned short* qn = qT + q_elems;
    float* P = (float*)(qn + q_elems);
    unsigned short* WT = (unsigned short*)(P + (size_t)SPL * p_elems);

    pack_kernel<<<dim3(NN / 64, C_ / 64, B_), 256, 0, stream>>>(in, qT, qn);
    gram_kernel<<<256, 512, 0, stream>>>(qT, P);
    softmax_kernel<<<dim3(C_ / 4, B_), 256, 0, stream>>>(P, WT);
    value_kernel<<<1024, 512, 0, stream>>>(qn, WT, gamma, out);
}